// Round 3
// baseline (341.853 us; speedup 1.0000x reference)
//
#include <hip/hip_runtime.h>
#include <type_traits>

namespace {
constexpr int HH = 512;
constexpr int WW = 512;
constexpr int KS = 11;
constexpr int PADR = 5;
constexpr int BH = 32;               // output rows per block (band)
constexpr int VR = 4;                // output rows per round (= rows staged)
constexpr int LP = 525;              // LDS pitch: 525 mod 32 = 13 -> phase-2
                                     // lane banks cover all 32 banks exactly
                                     // 2-way (free; verified pattern)
constexpr int NTHREADS = 256;
constexpr float SSIM_C1 = 1.0e-4f;   // (0.01*1.0)^2
constexpr float SSIM_C2 = 9.0e-4f;   // (0.03*1.0)^2
}

// Full-width band kernel, phase 1 fully scalarized.
// R1/R2 lesson: acc arrays inside the unrolled lambda were NOT SROA-promoted
// (R1: float2 acc[5][8] -> 650 MB scratch; R2: float a[4][2] x5 -> 104 MB
// scratch, VGPR stuck at 84, VALUBusy 28%). This version has ZERO arrays in
// phase 1: 40 named scalar accumulators, 11 named scalar weights, and a
// macro-expanded straight-line 14-row stream with literal (row, tap) pairs.
// Products x^2,y^2,xy computed once per input pixel, FMA'd into 4 output-row
// accumulators. Phase 2 keeps the R0-proven structure (no spill at VGPR 64).
__global__ __launch_bounds__(NTHREADS, 3) void ssim_fused(
    const float* __restrict__ x, const float* __restrict__ y,
    const float* __restrict__ kern, float* __restrict__ out)
{
    __shared__ float vb[5][VR][LP];   // 42000 B -> 3 blocks/CU (LDS-capped)

    const int bid = blockIdx.x;
    const int plane = bid >> 4;          // 16 bands per plane
    const int band  = bid & 15;
    const int tile_r = band * BH;

    const float* __restrict__ xp = x + (size_t)plane * (HH * WW);
    const float* __restrict__ yp = y + (size_t)plane * (HH * WW);
    float* __restrict__ op = out + (size_t)plane * (HH * WW);

    // 1D gaussian from the 2D kernel (exact for outer products), named scalars
    const float inv = rsqrtf(kern[5 * KS + 5]);
    const float w0 = kern[55] * inv, w1 = kern[56] * inv, w2 = kern[57] * inv,
                w3 = kern[58] * inv, w4 = kern[59] * inv, w5 = kern[60] * inv,
                w6 = kern[61] * inv, w7 = kern[62] * inv, w8 = kern[63] * inv,
                w9 = kern[64] * inv, w10 = kern[65] * inv;

    const int t = threadIdx.x;
    const int c0 = 2 * t;                // this thread's input columns

    // zero the horizontal pad columns once: [0,PADR) and [WW+PADR, LP)
    {
        constexpr int PPR = PADR + (LP - (WW + PADR));   // 5 + 8 = 13
        for (int i = t; i < 5 * VR * PPR; i += NTHREADS) {
            const int q = i / PPR;
            const int rm = i - q * PPR;
            const int col = (rm < PADR) ? rm : (WW + PADR + rm - PADR);
            (&vb[0][0][0])[q * LP + col] = 0.f;
        }
    }
    __syncthreads();

    const bool interior = (tile_r >= PADR) && (tile_r + BH + PADR <= HH);

    const int prow = (t >> 4) & 3;                 // phase-2 row 0..3
    const int pcg  = (t & 15) | ((t >> 6) << 4);   // phase-2 col group 0..63

#define DECL_O(o) \
    float a0_##o##_0 = 0.f, a0_##o##_1 = 0.f; \
    float a1_##o##_0 = 0.f, a1_##o##_1 = 0.f; \
    float a2_##o##_0 = 0.f, a2_##o##_1 = 0.f; \
    float a3_##o##_0 = 0.f, a3_##o##_1 = 0.f; \
    float a4_##o##_0 = 0.f, a4_##o##_1 = 0.f;

#define LOAD_K(k) \
    if (INTR) { \
        const float2 xv_ = *(const float2*)(xq + (ptrdiff_t)(k) * WW); \
        const float2 yv_ = *(const float2*)(yq + (ptrdiff_t)(k) * WW); \
        xv0 = xv_.x; xv1 = xv_.y; yv0 = yv_.x; yv1 = yv_.y; \
    } else { \
        const int rr_ = r0 - PADR + (k); \
        if (rr_ >= 0 && rr_ < HH) { \
            const float2 xv_ = *(const float2*)(xq + (ptrdiff_t)(k) * WW); \
            const float2 yv_ = *(const float2*)(yq + (ptrdiff_t)(k) * WW); \
            xv0 = xv_.x; xv1 = xv_.y; yv0 = yv_.x; yv1 = yv_.y; \
        } else { \
            xv0 = 0.f; xv1 = 0.f; yv0 = 0.f; yv1 = 0.f; \
        } \
    } \
    xx0 = xv0 * xv0; xx1 = xv1 * xv1; \
    yy0 = yv0 * yv0; yy1 = yv1 * yv1; \
    xy0 = xv0 * yv0; xy1 = xv1 * yv1;

#define TAP(o,j) \
    a0_##o##_0 += w##j * xv0;  a0_##o##_1 += w##j * xv1; \
    a1_##o##_0 += w##j * yv0;  a1_##o##_1 += w##j * yv1; \
    a2_##o##_0 += w##j * xx0;  a2_##o##_1 += w##j * xx1; \
    a3_##o##_0 += w##j * yy0;  a3_##o##_1 += w##j * yy1; \
    a4_##o##_0 += w##j * xy0;  a4_##o##_1 += w##j * xy1;

#define STORE_O(o) \
    vb[0][o][PADR + c0] = a0_##o##_0;  vb[0][o][PADR + c0 + 1] = a0_##o##_1; \
    vb[1][o][PADR + c0] = a1_##o##_0;  vb[1][o][PADR + c0 + 1] = a1_##o##_1; \
    vb[2][o][PADR + c0] = a2_##o##_0;  vb[2][o][PADR + c0 + 1] = a2_##o##_1; \
    vb[3][o][PADR + c0] = a3_##o##_0;  vb[3][o][PADR + c0 + 1] = a3_##o##_1; \
    vb[4][o][PADR + c0] = a4_##o##_0;  vb[4][o][PADR + c0 + 1] = a4_##o##_1;

    auto run_round = [&](int r0, auto intr_tag) {
        constexpr bool INTR = decltype(intr_tag)::value;

        // ---- phase 1: vertical 11-tap blur, 4 rows, straight-line, no arrays
        DECL_O(0) DECL_O(1) DECL_O(2) DECL_O(3)

        const float* xq = xp + (ptrdiff_t)(r0 - PADR) * WW + c0;
        const float* yq = yp + (ptrdiff_t)(r0 - PADR) * WW + c0;
        float xv0, xv1, yv0, yv1, xx0, xx1, yy0, yy1, xy0, xy1;

        LOAD_K(0)   TAP(0,0)
        LOAD_K(1)   TAP(0,1)  TAP(1,0)
        LOAD_K(2)   TAP(0,2)  TAP(1,1)  TAP(2,0)
        LOAD_K(3)   TAP(0,3)  TAP(1,2)  TAP(2,1)  TAP(3,0)
        LOAD_K(4)   TAP(0,4)  TAP(1,3)  TAP(2,2)  TAP(3,1)
        LOAD_K(5)   TAP(0,5)  TAP(1,4)  TAP(2,3)  TAP(3,2)
        LOAD_K(6)   TAP(0,6)  TAP(1,5)  TAP(2,4)  TAP(3,3)
        LOAD_K(7)   TAP(0,7)  TAP(1,6)  TAP(2,5)  TAP(3,4)
        LOAD_K(8)   TAP(0,8)  TAP(1,7)  TAP(2,6)  TAP(3,5)
        LOAD_K(9)   TAP(0,9)  TAP(1,8)  TAP(2,7)  TAP(3,6)
        LOAD_K(10)  TAP(0,10) TAP(1,9)  TAP(2,8)  TAP(3,7)
        LOAD_K(11)  TAP(1,10) TAP(2,9)  TAP(3,8)
        LOAD_K(12)  TAP(2,10) TAP(3,9)
        LOAD_K(13)  TAP(3,10)

        // ---- stage 4 rows into LDS (scalar writes; lanes stride-2 floats
        // -> 2-way banks, free)
        STORE_O(0) STORE_O(1) STORE_O(2) STORE_O(3)
        __syncthreads();

        // ---- phase 2: horizontal 11-tap blur + SSIM, 4 outputs x 2 passes
        // (R0-proven structure: no spill at VGPR 64)
#pragma unroll
        for (int pass = 0; pass < 2; ++pass) {
            const int ocol = (pcg + (pass << 6)) << 2;   // 0..508
            float res[5][4];
#pragma unroll
            for (int s = 0; s < 5; ++s) {
                float wnd[KS + 3];
#pragma unroll
                for (int i2 = 0; i2 < KS + 3; ++i2)
                    wnd[i2] = vb[s][prow][ocol + i2];
#pragma unroll
                for (int jj = 0; jj < 4; ++jj) {
                    res[s][jj] = w0 * wnd[jj]     + w1 * wnd[jj + 1]
                               + w2 * wnd[jj + 2] + w3 * wnd[jj + 3]
                               + w4 * wnd[jj + 4] + w5 * wnd[jj + 5]
                               + w6 * wnd[jj + 6] + w7 * wnd[jj + 7]
                               + w8 * wnd[jj + 8] + w9 * wnd[jj + 9]
                               + w10 * wnd[jj + 10];
                }
            }
            float4 o4;
#pragma unroll
            for (int jj = 0; jj < 4; ++jj) {
                const float ux = res[0][jj], uy = res[1][jj];
                const float uxx = res[2][jj], uyy = res[3][jj], uxy = res[4][jj];
                const float vx  = uxx - ux * ux;
                const float vy  = uyy - uy * uy;
                const float vxy = uxy - ux * uy;
                const float A1 = 2.f * ux * uy + SSIM_C1;
                const float A2 = 2.f * vxy + SSIM_C2;
                const float B1 = ux * ux + uy * uy + SSIM_C1;
                const float B2 = vx + vy + SSIM_C2;
                (&o4.x)[jj] = (A1 * A2) * __builtin_amdgcn_rcpf(B1 * B2);
            }
            *(float4*)(op + (size_t)(r0 + prow) * WW + ocol) = o4;
        }
        __syncthreads();   // LDS reused by next round
    };

    if (interior) {
        for (int j = 0; j < BH / VR; ++j)
            run_round(tile_r + j * VR, std::true_type{});
    } else {
        for (int j = 0; j < BH / VR; ++j)
            run_round(tile_r + j * VR, std::false_type{});
    }
}

extern "C" void kernel_launch(void* const* d_in, const int* in_sizes, int n_in,
                              void* d_out, int out_size, void* d_ws, size_t ws_size,
                              hipStream_t stream) {
    const float* x    = (const float*)d_in[0];
    const float* y    = (const float*)d_in[1];
    const float* kern = (const float*)d_in[2];
    float* out = (float*)d_out;

    const int nplanes = in_sizes[0] / (HH * WW);        // 48
    const int nblocks = nplanes * (HH / BH);            // 48 * 16 = 768

    ssim_fused<<<dim3(nblocks), dim3(NTHREADS), 0, stream>>>(x, y, kern, out);
}

// Round 4
// 212.471 us; speedup vs baseline: 1.6089x; 1.6089x over previous
//
#include <hip/hip_runtime.h>
#include <type_traits>

namespace {
constexpr int HH = 512;
constexpr int WW = 512;
constexpr int KS = 11;
constexpr int PADR = 5;
constexpr int TH = 32;                 // tile rows per block
constexpr int TW = 64;                 // tile cols per block
constexpr int SLAB = 16;               // rows per slab
constexpr int HC = TW + 2 * PADR;      // 74 columns incl. horizontal halo
constexpr int LP = 80;                 // pitch 80: rows 16B-aligned so phase-2
                                       // windows read as 4x ds_read_b128
                                       // (contiguous-256B-per-16-lane class)
constexpr int NTHREADS = 256;
constexpr float SSIM_C1 = 1.0e-4f;     // (0.01*1.0)^2
constexpr float SSIM_C2 = 9.0e-4f;     // (0.03*1.0)^2
}

// R0 structure (verified clean codegen: VGPR 64, WRITE=output-only, 137.5us)
// + two bounded upgrades:
//  - phase-1 ROW PAIRING: each position computes 2 consecutive output rows
//    from 12 shared input rows (products once per loaded pixel). 10 named
//    scalar accumulators -- R1/R2/R3 showed >=40 floats of phase-1 state
//    spills to scratch on this compiler; 10 is a small step above the
//    proven-clean 5. Loads/output 25->14, VALU/output ~102->84.
//  - phase-2 b128: pitch 80 aligns stat rows to 16B; the 14-float window
//    is read as 4 float4 LDS loads (was 14 scalar) -- ~3x fewer LDS-read
//    issue cycles and 50 fewer instructions per position.
__global__ __launch_bounds__(NTHREADS, 4) void ssim_fused(
    const float* __restrict__ x, const float* __restrict__ y,
    const float* __restrict__ kern, float* __restrict__ out)
{
    __shared__ float vb[5][SLAB][LP];   // 25600 B -> 4 blocks/CU

    constexpr int tiles_w = WW / TW;         // 8
    constexpr int tiles_h = HH / TH;         // 16
    constexpr int tpp = tiles_w * tiles_h;   // 128 tiles per plane

    const int bid = blockIdx.x;
    const int plane = bid / tpp;
    const int trem = bid - plane * tpp;
    const int tr_idx = trem / tiles_w;
    const int tile_r = tr_idx * TH;
    const int tile_c = (trem - tr_idx * tiles_w) * TW;

    const float* __restrict__ xp = x + (size_t)plane * (HH * WW);
    const float* __restrict__ yp = y + (size_t)plane * (HH * WW);
    float* __restrict__ op = out + (size_t)plane * (HH * WW);

    // 1D gaussian from the 2D kernel (exact for outer products)
    float wt[KS];
    {
        const float c = kern[5 * KS + 5];
        const float inv = rsqrtf(c);
#pragma unroll
        for (int i = 0; i < KS; ++i) wt[i] = kern[5 * KS + i] * inv;
    }

    const int t = threadIdx.x;
    const bool interior = (tile_r >= PADR) && (tile_r + TH + PADR <= HH) &&
                          (tile_c >= PADR) && (tile_c + TW + PADR <= WW);

    // phase-2 mapping: one 4-wide output group per thread per slab
    const int p2_r = t >> 4;           // 0..15
    const int p2_c0 = (t & 15) * 4;    // 0..60

    auto run_slab = [&](int s0, auto intr_tag) {
        constexpr bool INTR = decltype(intr_tag)::value;
        // ---- phase 1: vertical 11-tap blur into LDS, ROW PAIRS.
        // 8 row-pairs x 74 cols = 592 positions; each does 12 loads/array,
        // products computed once, FMA into 2x5 named accumulators.
        for (int i = t; i < (SLAB / 2) * HC; i += NTHREADS) {
            const int r2 = i / HC;
            const int c = i - r2 * HC;
            const int gr = tile_r + s0 + 2 * r2;   // first output row of pair
            const int gc = tile_c + c - PADR;      // input col (maybe OOB)
            float sxA = 0.f, syA = 0.f, sxxA = 0.f, syyA = 0.f, sxyA = 0.f;
            float sxB = 0.f, syB = 0.f, sxxB = 0.f, syyB = 0.f, sxyB = 0.f;
            if (INTR) {
                const float* xq = xp + (gr - PADR) * WW + gc;
                const float* yq = yp + (gr - PADR) * WW + gc;
#pragma unroll
                for (int k = 0; k < KS + 1; ++k) {       // 12 input rows
                    const float xv = xq[k * WW];
                    const float yv = yq[k * WW];
                    const float xx = xv * xv;
                    const float yy = yv * yv;
                    const float xy = xv * yv;
                    if (k < KS) {                        // row A taps 0..10
                        const float w = wt[k];
                        sxA += w * xv;  syA += w * yv;
                        sxxA += w * xx; syyA += w * yy; sxyA += w * xy;
                    }
                    if (k >= 1) {                        // row B taps 0..10
                        const float w = wt[k - 1];
                        sxB += w * xv;  syB += w * yv;
                        sxxB += w * xx; syyB += w * yy; sxyB += w * xy;
                    }
                }
            } else {
                const bool cok = (gc >= 0) & (gc < WW);
#pragma unroll
                for (int k = 0; k < KS + 1; ++k) {
                    const int rr = gr - PADR + k;
                    const bool ok = cok & (rr >= 0) & (rr < HH);
                    float xv = 0.f, yv = 0.f;
                    if (ok) {
                        xv = xp[rr * WW + gc];
                        yv = yp[rr * WW + gc];
                    }
                    const float xx = xv * xv;
                    const float yy = yv * yv;
                    const float xy = xv * yv;
                    if (k < KS) {
                        const float w = wt[k];
                        sxA += w * xv;  syA += w * yv;
                        sxxA += w * xx; syyA += w * yy; sxyA += w * xy;
                    }
                    if (k >= 1) {
                        const float w = wt[k - 1];
                        sxB += w * xv;  syB += w * yv;
                        sxxB += w * xx; syyB += w * yy; sxyB += w * xy;
                    }
                }
            }
            const int rA = 2 * r2, rB = 2 * r2 + 1;
            vb[0][rA][c] = sxA;   vb[0][rB][c] = sxB;
            vb[1][rA][c] = syA;   vb[1][rB][c] = syB;
            vb[2][rA][c] = sxxA;  vb[2][rB][c] = sxxB;
            vb[3][rA][c] = syyA;  vb[3][rB][c] = syyB;
            vb[4][rA][c] = sxyA;  vb[4][rB][c] = sxyB;
        }
        __syncthreads();

        // ---- phase 2: horizontal 11-tap blur + SSIM, 4 outputs per thread.
        // Window [p2_c0, p2_c0+14) read as 4 aligned float4 LDS loads.
        float res[5][4];
#pragma unroll
        for (int s = 0; s < 5; ++s) {
            const float4 q0 = *(const float4*)&vb[s][p2_r][p2_c0];
            const float4 q1 = *(const float4*)&vb[s][p2_r][p2_c0 + 4];
            const float4 q2 = *(const float4*)&vb[s][p2_r][p2_c0 + 8];
            const float4 q3 = *(const float4*)&vb[s][p2_r][p2_c0 + 12];
            float wnd[16] = {q0.x, q0.y, q0.z, q0.w,
                             q1.x, q1.y, q1.z, q1.w,
                             q2.x, q2.y, q2.z, q2.w,
                             q3.x, q3.y, q3.z, q3.w};
#pragma unroll
            for (int j = 0; j < 4; ++j) {
                float a = 0.f;
#pragma unroll
                for (int k = 0; k < KS; ++k) a += wt[k] * wnd[j + k];
                res[s][j] = a;
            }
        }
        float4 o4;
#pragma unroll
        for (int j = 0; j < 4; ++j) {
            const float ux = res[0][j], uy = res[1][j];
            const float uxx = res[2][j], uyy = res[3][j], uxy = res[4][j];
            const float vx  = uxx - ux * ux;
            const float vy  = uyy - uy * uy;
            const float vxy = uxy - ux * uy;
            const float a1 = 2.f * ux * uy + SSIM_C1;
            const float a2 = 2.f * vxy + SSIM_C2;
            const float b1 = ux * ux + uy * uy + SSIM_C1;
            const float b2 = vx + vy + SSIM_C2;
            (&o4.x)[j] = (a1 * a2) * __builtin_amdgcn_rcpf(b1 * b2);
        }
        *(float4*)(op + (size_t)(tile_r + s0 + p2_r) * WW + (tile_c + p2_c0)) = o4;
        __syncthreads();   // LDS reused by next slab
    };

    if (interior) {
        run_slab(0,    std::true_type{});
        run_slab(SLAB, std::true_type{});
    } else {
        run_slab(0,    std::false_type{});
        run_slab(SLAB, std::false_type{});
    }
}

extern "C" void kernel_launch(void* const* d_in, const int* in_sizes, int n_in,
                              void* d_out, int out_size, void* d_ws, size_t ws_size,
                              hipStream_t stream) {
    const float* x    = (const float*)d_in[0];
    const float* y    = (const float*)d_in[1];
    const float* kern = (const float*)d_in[2];
    float* out = (float*)d_out;

    const int nplanes = in_sizes[0] / (HH * WW);            // 48
    const int nblocks = nplanes * (HH / TH) * (WW / TW);    // 6144

    ssim_fused<<<dim3(nblocks), dim3(NTHREADS), 0, stream>>>(x, y, kern, out);
}